// Round 5
// baseline (39.986 us; speedup 1.0000x reference)
//
#include <hip/hip_runtime.h>

#define CI 32
#define CO 32
#define PD 64
#define QDIM 1024
#define M_TOTAL (32*4096)
#define WG_THREADS 512
#define NBLK 512
#define TILE_M 64
#define NT 8   // (2048 m-tiles * 2 col-halves) / 512 WGs

typedef float  f32x2  __attribute__((ext_vector_type(2)));
typedef float  f32x4  __attribute__((ext_vector_type(4)));
typedef __bf16 bf16x4 __attribute__((ext_vector_type(4)));
typedef __bf16 bf16x8 __attribute__((ext_vector_type(8)));

#define XL_STRIDE 72   // 64 f32 + 8 pad (transposed X)
#define OL_STRIDE 20   // 16 f32 + 4 pad (output staging, 16 cols per WG)

// ---- one-time: Wk [64][1024] f32  ->  wsT [1024][64] bf16 (column-major Wk) ----
__global__ __launch_bounds__(256)
void wk_transpose_kernel(const float* __restrict__ Wk, __bf16* __restrict__ wsT)
{
    __shared__ float tile[64][68];
    const int q0 = blockIdx.x * 64;
    const int t  = threadIdx.x;
#pragma unroll
    for (int rr = 0; rr < 4; ++rr) {
        const int k = (t >> 4) + rr * 16;
        const int cc = (t & 15) * 4;
        f32x4 v = *(const f32x4*)(Wk + (size_t)k * QDIM + q0 + cc);
        tile[k][cc] = v[0]; tile[k][cc+1] = v[1]; tile[k][cc+2] = v[2]; tile[k][cc+3] = v[3];
    }
    __syncthreads();
    const int qq = t >> 2, ks = (t & 3) * 16;
    bf16x8 o0, o1;
#pragma unroll
    for (int j = 0; j < 8; ++j) { o0[j] = (__bf16)tile[ks + j][qq]; o1[j] = (__bf16)tile[ks + 8 + j][qq]; }
    *(bf16x8*)(wsT + (size_t)(q0 + qq) * PD + ks)     = o0;
    *(bf16x8*)(wsT + (size_t)(q0 + qq) * PD + ks + 8) = o1;
}

__global__ __launch_bounds__(WG_THREADS, 4)
void cond_dense_kernel(const float* __restrict__ Xg, const float* __restrict__ Pg,
                       const __bf16* __restrict__ wsT, float* __restrict__ outg)
{
    __shared__ __bf16 Pl[TILE_M * PD];          // 8 KB, 16B-granule XOR-swizzled
    __shared__ float  Xl[CI * XL_STRIDE];       // 9 KB, transposed
    __shared__ float  Ol[TILE_M * OL_STRIDE];   // 5 KB

    const int tid = threadIdx.x;
    const int l   = tid & 63;
    const int w   = tid >> 6;   // wave 0..7: owns output cols o' = 2w, 2w+1 (within half)
    const int h   = l >> 4;     // 0..3 (k-group)
    const int c   = l & 15;     // MFMA col index
    const int di  = c >> 1;     // 0..7: i = 8t + di
    const int dq  = c & 1;      // 0..1: o' = 2w + dq

    const int col0  = (blockIdx.x >> 8) * 16;        // col-half: blocks b and b+256 pair
    const int tbase = (blockIdx.x & 255) * NT;       // same tile halves -> same XCD (b%8)

    // ---- B fragments: only 32 VGPRs/wave (2 cols x full i) -> compiler keeps resident ----
    bf16x8 bfrag[4][2];
#pragma unroll
    for (int t = 0; t < 4; ++t) {
        const int q = (8*t + di) * CO + col0 + 2*w + dq;
#pragma unroll
        for (int s = 0; s < 2; ++s)
            bfrag[t][s] = *(const bf16x8*)(wsT + (size_t)q * PD + s*32 + h*8);
    }
#pragma unroll
    for (int t = 0; t < 4; ++t)   // pin: forbid re-sinking the loads into the loop
        asm volatile("" : "+v"(bfrag[t][0]), "+v"(bfrag[t][1]));

    // ---- staging assignments (coalesced f32x4 global reads) ----
    const int prow = tid >> 4;        // P rows 0..31 (and +32)
    const int pg   = (tid & 15) >> 1; // 16B granule 0..7 within row
    const int ph8  = (tid & 1) * 8;   // 8B half within granule
    const int pcol = (tid & 15) * 4;
    const int xrow = tid >> 3;        // X rows 0..63
    const int xcol = (tid & 7) * 4;

    f32x4 pr0, pr1, xr;
    auto load_stage = [&](int tile) {
        const float* Pb = Pg + (size_t)tile * TILE_M * PD;
        const float* Xb = Xg + (size_t)tile * TILE_M * CI;
        pr0 = *(const f32x4*)(Pb + prow * PD + pcol);
        pr1 = *(const f32x4*)(Pb + (prow + 32) * PD + pcol);
        xr  = *(const f32x4*)(Xb + xrow * CI + xcol);
    };
    auto pl_ptr = [&](int row) -> __bf16* {   // swizzled: granule ^ (row&7)
        return (__bf16*)((char*)Pl + row * 128 + (((pg ^ (row & 7)) << 4) | ph8));
    };
    auto write_lds = [&]() {
        bf16x4 a0, a1;
#pragma unroll
        for (int j = 0; j < 4; ++j) { a0[j] = (__bf16)pr0[j]; a1[j] = (__bf16)pr1[j]; }
        *(bf16x4*)pl_ptr(prow)      = a0;
        *(bf16x4*)pl_ptr(prow + 32) = a1;
#pragma unroll
        for (int j = 0; j < 4; ++j) Xl[(xcol + j) * XL_STRIDE + xrow] = xr[j];
    };

    load_stage(tbase);
    write_lds();
    __syncthreads();

    for (int it = 0; it < NT; ++it) {
        const int tile = tbase + it;
        if (it + 1 < NT) load_stage(tile + 1);   // issue next tile's loads early (T14)

#pragma unroll
        for (int sub = 0; sub < 4; ++sub) {
            const int m0 = sub * 16;
            // A-frags: row m0+c, k-granule (h+4s) ^ (c&7)  -> <=2-way banks
            const char* prow_b = (const char*)Pl + (m0 + c) * 128;
            bf16x8 af0 = *(const bf16x8*)(prow_b + (((h    ) ^ (c & 7)) << 4));
            bf16x8 af1 = *(const bf16x8*)(prow_b + (((h + 4) ^ (c & 7)) << 4));

            f32x4 acc[4] = {};
#pragma unroll
            for (int t = 0; t < 4; ++t) {
                acc[t] = __builtin_amdgcn_mfma_f32_16x16x32_bf16(af0, bfrag[t][0], acc[t], 0, 0, 0);
                acc[t] = __builtin_amdgcn_mfma_f32_16x16x32_bf16(af1, bfrag[t][1], acc[t], 0, 0, 0);
            }
            // epilogue: out[m, o] = sum_i relu(W[m,i,o]) * X[m,i],  i = 8t+di
            f32x4 part = {};
#pragma unroll
            for (int t = 0; t < 4; ++t) {
                const int i = 8*t + di;
                f32x4 xv = *(const f32x4*)(&Xl[i * XL_STRIDE + m0 + h*4]);
#pragma unroll
                for (int r = 0; r < 4; ++r)
                    part[r] += fmaxf(acc[t][r], 0.0f) * xv[r];
            }
            // transpose-reduce over di (3 lane bits: xor 2,4 transpose + xor 8 plain add)
            const bool b0 = (di & 1) != 0, b1 = (di & 2) != 0;
            const float lo_k = b0 ? part[1] : part[0];
            const float lo_s = b0 ? part[0] : part[1];
            const float hi_k = b0 ? part[3] : part[2];
            const float hi_s = b0 ? part[2] : part[3];
            const float u = lo_k + __shfl_xor(lo_s, 2);
            const float v = hi_k + __shfl_xor(hi_s, 2);
            const float keep = b1 ? v : u;
            const float send = b1 ? u : v;
            const float hf  = keep + __shfl_xor(send, 4);   // comp di&3, half i-sum
            const float res = hf + __shfl_xor(hf, 8);       // full i-sum (dup di&4 pairs)
            if ((di & 4) == 0)
                Ol[(m0 + h*4 + (di & 3)) * OL_STRIDE + 2*w + dq] = res;
        }

        __syncthreads();   // Ol complete; Pl/Xl reads complete

        // store: 64 rows x 16 cols; 8B/thread, 64B contiguous per row (HBM sector)
        {
            float* outp = outg + (size_t)tile * TILE_M * CO + col0;
            const int row = tid >> 3, cc = (tid & 7) * 2;
            f32x2 o = *(const f32x2*)(&Ol[row * OL_STRIDE + cc]);
            *(f32x2*)(outp + row * CO + cc) = o;
        }

        if (it + 1 < NT) {
            write_lds();          // Pl/Xl reads drained at barrier above; Ol untouched
            __syncthreads();
        }
    }
}

extern "C" void kernel_launch(void* const* d_in, const int* in_sizes, int n_in,
                              void* d_out, int out_size, void* d_ws, size_t ws_size,
                              hipStream_t stream)
{
    const float* X  = (const float*)d_in[0];
    const float* P  = (const float*)d_in[1];
    const float* Wk = (const float*)d_in[2];
    float* out = (float*)d_out;
    __bf16* wsT = (__bf16*)d_ws;   // 1024*64*2 = 128 KB

    wk_transpose_kernel<<<dim3(QDIM / 64), dim3(256), 0, stream>>>(Wk, wsT);
    cond_dense_kernel<<<dim3(NBLK), dim3(WG_THREADS), 0, stream>>>(X, P, wsT, out);
}